// Round 5
// baseline (5520.351 us; speedup 1.0000x reference)
//
#include <hip/hip_runtime.h>
#include <hip/hip_cooperative_groups.h>

namespace cg = cooperative_groups;

#define DEV __device__ __forceinline__

constexpr int L_ = 24, E_ = 1024, H_ = 16, HD_ = 64, S_ = 2048;
constexpr int NCHUNK = 256, CHUNK = 8;
constexpr int GRID = 256;
constexpr int NACC = 8;                 // contention-striped accumulator copies
static_assert(NCHUNK == GRID, "attn stage assumes one chunk per block");

// ws layout (float offsets)
constexpr int WS_HRES = 0;       // residual input h of current layer
constexpr int WS_QKV  = 1024;    // q|k|v (3072)
constexpr int WS_WO   = 5120;    // vals@Wo + bo
constexpr int WS_HA   = 6144;    // hA = LN1(h + wo_out)
constexpr int WS_FFT  = 7168;    // hA@W1 + b1 (pre-relu)
constexpr int WS_FFO  = 8192;    // relu(.)@W2 + b2
constexpr int WS_LACC = 9216;    // NACC*16   softmax denominators (per head)
constexpr int WS_NACC = 9344;    // NACC*1024 softmax numerators  (per head*dim)
constexpr int ACC_FLOATS = NACC * (16 + 1024);  // 8320, zeroed per layer
constexpr int WS_BAR  = 18432;   // 320 u32: 8 sub-counters (padded x32), master, gen

struct SMemG { float racc[256]; float x[E_]; float red[8]; };  // gemv stages
struct SMemA { float o[4096]; float l[4][64]; };               // attn merge
union alignas(16) SMemU { SMemG g; SMemA a; };

struct Params {
  const int* xi;
  const float *cache1, *cache2;
  const float *et, *eid, *ex, *ey, *etm;
  const float *lnes, *lneb;
  const float *Wv, *Wq, *Wk, *Wo, *W1, *W2;
  const float *bv, *bq, *bk, *bo, *b1, *b2;
  const float *ln1s, *ln1b, *ln2s, *ln2b;
  const float *Wpi, *bpi, *Wvh, *bvh, *Wc, *bc;
  float *ws, *out, *oc1, *oc2;
};

DEV float dot4(float4 a, float4 b) { return a.x*b.x + a.y*b.y + a.z*b.z + a.w*b.w; }
DEV int nz4(float4 v) { return (v.x != 0.f) || (v.y != 0.f) || (v.z != 0.f) || (v.w != 0.f); }
DEV float4 fma4(float4 o, float p, float4 v) {
  return make_float4(o.x + p*v.x, o.y + p*v.y, o.z + p*v.z, o.w + p*v.w);
}
// store 16 consecutive floats at p where (uintptr_t)p % 16 == 12
DEV void store16_off12(float* p, float4 a, float4 b, float4 c, float4 d) {
  p[0] = a.x;
  *(float4*)(p + 1) = make_float4(a.y, a.z, a.w, b.x);
  *(float4*)(p + 5) = make_float4(b.y, b.z, b.w, c.x);
  *(float4*)(p + 9) = make_float4(c.y, c.z, c.w, d.x);
  p[13] = d.y; p[14] = d.z; p[15] = d.w;
}

// two-level sense-reversing grid barrier: 8 padded sub-counters -> master -> gen.
// Device-scope release/acquire chain through the RMWs == cg::grid_group::sync
// semantics, but arrival contention is 32+8 same-address RMWs instead of 256.
// g0 is loaded BEFORE the ACQ_REL arrival-add (release half pins the order),
// so a late spinner can never miss the generation bump.
DEV void gbar(float* wsf, int bid) {
  __syncthreads();
  if (threadIdx.x == 0) {
    unsigned* bar = (unsigned*)(wsf + WS_BAR);
    unsigned* sub = bar + (bid & 7) * 32;   // 128B-padded per group
    unsigned* master = bar + 256;
    unsigned* gen = bar + 288;
    __threadfence();
    unsigned g0 = __hip_atomic_load(gen, __ATOMIC_RELAXED, __HIP_MEMORY_SCOPE_AGENT);
    unsigned a = __hip_atomic_fetch_add(sub, 1u, __ATOMIC_ACQ_REL, __HIP_MEMORY_SCOPE_AGENT);
    bool bumped = false;
    if (a == 31) {                          // last of this group of 32
      __hip_atomic_store(sub, 0u, __ATOMIC_RELAXED, __HIP_MEMORY_SCOPE_AGENT);
      unsigned m = __hip_atomic_fetch_add(master, 1u, __ATOMIC_ACQ_REL, __HIP_MEMORY_SCOPE_AGENT);
      if (m == 7) {                         // global last
        __hip_atomic_store(master, 0u, __ATOMIC_RELAXED, __HIP_MEMORY_SCOPE_AGENT);
        __hip_atomic_store(gen, g0 + 1u, __ATOMIC_RELEASE, __HIP_MEMORY_SCOPE_AGENT);
        bumped = true;
      }
    }
    if (!bumped) {
      while (__hip_atomic_load(gen, __ATOMIC_ACQUIRE, __HIP_MEMORY_SCOPE_AGENT) == g0)
        __builtin_amdgcn_s_sleep(2);
    }
  }
  __syncthreads();
}

// wave-shuffle block reduce: 2 barriers (first protects `red` reuse)
DEV float block_reduce_sum(float v, float* red) {
#pragma unroll
  for (int st = 32; st > 0; st >>= 1) v += __shfl_xor(v, st);
  int t = threadIdx.x;
  __syncthreads();
  if ((t & 63) == 0) red[t >> 6] = v;
  __syncthreads();
  return red[0] + red[1] + red[2] + red[3];
}

// y = LN(a + b) * sc + bi into x_lds[1024]; ends with barrier
DEV void block_ln(const float* __restrict__ a, const float* __restrict__ b,
                  const float* __restrict__ sc, const float* __restrict__ bi,
                  float eps, float* x_lds, float* red) {
  int t = threadIdx.x;
  float v[4]; float s = 0.f;
#pragma unroll
  for (int j = 0; j < 4; ++j) {
    int idx = t * 4 + j;
    float x = a[idx] + (b ? b[idx] : 0.f);
    v[j] = x; s += x;
  }
  float mean = block_reduce_sum(s, red) * (1.f / E_);
  float vs = 0.f;
#pragma unroll
  for (int j = 0; j < 4; ++j) { float d = v[j] - mean; vs += d * d; }
  float var = block_reduce_sum(vs, red) * (1.f / E_);
  float rstd = rsqrtf(var + eps);
#pragma unroll
  for (int j = 0; j < 4; ++j) {
    int idx = t * 4 + j;
    x_lds[idx] = (v[j] - mean) * rstd * sc[idx] + bi[idx];
  }
  __syncthreads();
}

// load this thread's 4 float4 rows of a 64x64 weight tile into registers.
// Issued at the TOP of each stage so HBM latency overlaps the x-producing
// phase (LN / merge / relu) that follows — the compiler won't hoist these
// across __syncthreads on its own.
DEV void tile_load(const float* __restrict__ W, int col0, int row0, float4 w[4]) {
  int t = threadIdx.x;
  int c4 = t & 15, g = t >> 4;
  const float* Wp = W + (size_t)row0 * E_ + col0 + 4 * c4;
#pragma unroll
  for (int r4 = 0; r4 < 4; ++r4)
    w[r4] = *(const float4*)(Wp + (size_t)(r4 * 16 + g) * E_);
}

// cross-wave reduce of per-thread float4 partials + atomic accumulate to out
DEV void red_store(float4 acc, float* __restrict__ out, int col0, float4* racc) {
  int t = threadIdx.x, lane = t & 63, wv = t >> 6;
  acc.x += __shfl_xor(acc.x, 16); acc.y += __shfl_xor(acc.y, 16);
  acc.z += __shfl_xor(acc.z, 16); acc.w += __shfl_xor(acc.w, 16);
  acc.x += __shfl_xor(acc.x, 32); acc.y += __shfl_xor(acc.y, 32);
  acc.z += __shfl_xor(acc.z, 32); acc.w += __shfl_xor(acc.w, 32);
  if (lane < 16) racc[wv * 16 + lane] = acc;  // lane == c4 here
  __syncthreads();
  if (t < 16) {
    float4 a0 = racc[t], a1 = racc[16 + t], a2 = racc[32 + t], a3 = racc[48 + t];
    atomicAdd(&out[col0 + 4*t + 0], a0.x + a1.x + a2.x + a3.x);
    atomicAdd(&out[col0 + 4*t + 1], a0.y + a1.y + a2.y + a3.y);
    atomicAdd(&out[col0 + 4*t + 2], a0.z + a1.z + a2.z + a3.z);
    atomicAdd(&out[col0 + 4*t + 3], a0.w + a1.w + a2.w + a3.w);
  }
  __syncthreads();  // protect racc before next item
}

// FMA against pre-loaded tile registers, then reduce+store
DEV void tile_fma_store(const float4 w[4], const float* __restrict__ x,
                        int col0, int row0, float* __restrict__ out, float4* racc) {
  int g = threadIdx.x >> 4;
  float x0 = x[row0 + g],      x1 = x[row0 + 16 + g];
  float x2 = x[row0 + 32 + g], x3 = x[row0 + 48 + g];
  float4 acc;
  acc.x = x0*w[0].x + x1*w[1].x + x2*w[2].x + x3*w[3].x;
  acc.y = x0*w[0].y + x1*w[1].y + x2*w[2].y + x3*w[3].y;
  acc.z = x0*w[0].z + x1*w[1].z + x2*w[2].z + x3*w[3].z;
  acc.w = x0*w[0].w + x1*w[1].w + x2*w[2].w + x3*w[3].w;
  red_store(acc, out, col0, racc);
}

DEV void embed_stage(const Params& p, SMemU& s, float* __restrict__ ws) {
  int t = threadIdx.x;
  int i0 = p.xi[0], i1 = p.xi[1], i2 = p.xi[2], i3 = p.xi[3], i4 = p.xi[4];
  float v[4]; float sum = 0.f;
#pragma unroll
  for (int j = 0; j < 4; ++j) {
    int idx = t * 4 + j;
    float val = p.et[i0 * E_ + idx] + p.eid[i1 * E_ + idx] + p.ex[i2 * E_ + idx]
              + p.ey[i3 * E_ + idx] + p.etm[i4 * E_ + idx];
    v[j] = val; sum += val;
  }
  float mean = block_reduce_sum(sum, s.g.red) * (1.f / E_);
  float vs = 0.f;
#pragma unroll
  for (int j = 0; j < 4; ++j) { float d = v[j] - mean; vs += d * d; }
  float var = block_reduce_sum(vs, s.g.red) * (1.f / E_);
  float rstd = rsqrtf(var + 1e-12f);
#pragma unroll
  for (int j = 0; j < 4; ++j) {
    int idx = t * 4 + j;
    ws[WS_HRES + idx] = (v[j] - mean) * rstd * p.lnes[idx] + p.lneb[idx];
    ws[WS_QKV + idx]          = p.bq[idx];
    ws[WS_QKV + E_ + idx]     = p.bk[idx];
    ws[WS_QKV + 2 * E_ + idx] = p.bv[idx];
    ws[WS_WO + idx]           = p.bo[idx];      // layer-0 bo
  }
  for (int k = t; k < ACC_FLOATS; k += 256) ws[WS_LACC + k] = 0.f;  // layer-0 acc
  // barrier state init (published by the one cg sync that follows)
  unsigned* bar = (unsigned*)(ws + WS_BAR);
  for (int k = t; k < 320; k += 256) bar[k] = 0u;
}

// flash-attention chunk (max-free: scores bounded) + fused cache shift;
// per-chunk partials merged in LDS then atomicAdd'ed into NACC striped copies
DEV void attn_stage(const Params& p, SMemU& s, float* __restrict__ ws, int layer, int item) {
  const float* c1 = p.cache1 + (size_t)layer * S_ * E_;
  const float* c2 = p.cache2 + (size_t)layer * S_ * E_;
  float* o1 = p.oc1 + (size_t)layer * S_ * E_;
  float* o2 = p.oc2 + (size_t)layer * S_ * E_;
  const float* qbuf = ws + WS_QKV;
  const float* knew = ws + WS_QKV + E_;
  const float* vnew = ws + WS_QKV + 2 * E_;

  int t = threadIdx.x;
  int wv = t >> 6, lane = t & 63;
  int h = lane >> 2, g = lane & 3;
  int off = h * HD_ + g * 16;

  const float4* q4 = (const float4*)(qbuf + off);
  float4 qa = q4[0], qb = q4[1], qc = q4[2], qd = q4[3];

  float l = 0.f;
  float4 oa = make_float4(0,0,0,0), ob = oa, occ = oa, od = oa;

#pragma unroll
  for (int pp = 0; pp < 2; ++pp) {
    int sout = item * CHUNK + wv * 2 + pp;
    const float4 *kp, *vp;
    if (sout < S_ - 1) {
      kp = (const float4*)(c2 + (size_t)(sout + 1) * E_ + off);
      vp = (const float4*)(c1 + (size_t)(sout + 1) * E_ + off);
    } else {
      kp = (const float4*)(knew + off);
      vp = (const float4*)(vnew + off);
    }
    float4 ka = kp[0], kb = kp[1], kc = kp[2], kd = kp[3];
    float4 va = vp[0], vb = vp[1], vc = vp[2], vd = vp[3];
    float dot = dot4(qa, ka) + dot4(qb, kb) + dot4(qc, kc) + dot4(qd, kd);
    dot += __shfl_xor(dot, 1);
    dot += __shfl_xor(dot, 2);
    float score = dot * 0.125f;
    int nz = nz4(va) | nz4(vb) | nz4(vc) | nz4(vd);
    bool msk = (__ballot(nz) != 0ULL);
    float pw = msk ? __expf(score) : 0.f;   // |score| << 88 by construction
    l += pw;
    oa = fma4(oa, pw, va); ob = fma4(ob, pw, vb);
    occ = fma4(occ, pw, vc); od = fma4(od, pw, vd);
    store16_off12(o1 + (size_t)sout * E_ + off, va, vb, vc, vd);
    store16_off12(o2 + (size_t)sout * E_ + off, ka, kb, kc, kd);
  }

  float4* so = (float4*)s.a.o;
  s.a.l[wv][lane] = l;
  so[(wv * 64 + lane) * 4 + 0] = oa;
  so[(wv * 64 + lane) * 4 + 1] = ob;
  so[(wv * 64 + lane) * 4 + 2] = occ;
  so[(wv * 64 + lane) * 4 + 3] = od;
  __syncthreads();
  if (t < 64) {
    float Lt = s.a.l[0][lane] + s.a.l[1][lane] + s.a.l[2][lane] + s.a.l[3][lane];
    float4 ra = make_float4(0,0,0,0), rb = ra, rc = ra, rd = ra;
#pragma unroll
    for (int w = 0; w < 4; ++w) {
      ra = fma4(ra, 1.f, so[(w * 64 + lane) * 4 + 0]);
      rb = fma4(rb, 1.f, so[(w * 64 + lane) * 4 + 1]);
      rc = fma4(rc, 1.f, so[(w * 64 + lane) * 4 + 2]);
      rd = fma4(rd, 1.f, so[(w * 64 + lane) * 4 + 3]);
    }
    int copy = item & (NACC - 1);
    float* nacc = ws + WS_NACC + copy * E_ + off;
    atomicAdd(&nacc[0],  ra.x); atomicAdd(&nacc[1],  ra.y);
    atomicAdd(&nacc[2],  ra.z); atomicAdd(&nacc[3],  ra.w);
    atomicAdd(&nacc[4],  rb.x); atomicAdd(&nacc[5],  rb.y);
    atomicAdd(&nacc[6],  rb.z); atomicAdd(&nacc[7],  rb.w);
    atomicAdd(&nacc[8],  rc.x); atomicAdd(&nacc[9],  rc.y);
    atomicAdd(&nacc[10], rc.z); atomicAdd(&nacc[11], rc.w);
    atomicAdd(&nacc[12], rd.x); atomicAdd(&nacc[13], rd.y);
    atomicAdd(&nacc[14], rd.z); atomicAdd(&nacc[15], rd.w);
    if (g == 0) atomicAdd(&ws[WS_LACC + copy * 16 + h], Lt);
  }
}

DEV void final_stage(const Params& p, SMemU& s, float* __restrict__ ws) {
  block_ln(ws + WS_HA, ws + WS_FFO, p.ln2s + (size_t)(L_ - 1) * E_,
           p.ln2b + (size_t)(L_ - 1) * E_, 1e-6f, s.g.x, s.g.red);
  int t = threadIdx.x, wv = t >> 6, lane = t & 63;
  for (int j = wv; j < 47; j += 4) {
    const float* W; int nc, cj; float bb;
    if (j < 32)      { W = p.Wpi; nc = 32; cj = j;      bb = p.bpi[cj]; }
    else if (j < 39) { W = p.Wvh; nc = 7;  cj = j - 32; bb = p.bvh[cj]; }
    else             { W = p.Wc;  nc = 8;  cj = j - 39; bb = p.bc[cj]; }
    float a = 0.f;
#pragma unroll
    for (int it = 0; it < 16; ++it) {
      int k = lane * 16 + it;
      a += s.g.x[k] * W[(size_t)k * nc + cj];
    }
    a += __shfl_xor(a, 1);  a += __shfl_xor(a, 2);  a += __shfl_xor(a, 4);
    a += __shfl_xor(a, 8);  a += __shfl_xor(a, 16); a += __shfl_xor(a, 32);
    if (lane == 0) p.out[j] = a + bb;
  }
}

__global__ __launch_bounds__(256) void k_net(Params p) {
  cg::grid_group gg = cg::this_grid();
  __shared__ SMemU s;
  float* ws = p.ws;
  const int bid = blockIdx.x;
  const int t = threadIdx.x;

  if (bid == 0) embed_stage(p, s, ws);
  gg.sync();   // publishes embed outputs AND barrier-state init

  for (int i = 0; i < L_; ++i) {
    // ---- stage qkv: prefetch 3 weight tiles, THEN x = LN2(prev)/hres ----
    {
      int col0 = ((bid >> 4) & 15) * 64, row0 = (bid & 15) * 64;
      float4 wq[4], wk[4], wv4[4];
      tile_load(p.Wq + (size_t)i * E_ * E_, col0, row0, wq);
      tile_load(p.Wk + (size_t)i * E_ * E_, col0, row0, wk);
      tile_load(p.Wv + (size_t)i * E_ * E_, col0, row0, wv4);
      if (i == 0) {
#pragma unroll
        for (int j = 0; j < 4; ++j) s.g.x[t * 4 + j] = ws[WS_HRES + t * 4 + j];
        __syncthreads();
      } else {
        block_ln(ws + WS_HA, ws + WS_FFO, p.ln2s + (size_t)(i - 1) * E_,
                 p.ln2b + (size_t)(i - 1) * E_, 1e-6f, s.g.x, s.g.red);
        if (bid == 0) {
#pragma unroll
          for (int j = 0; j < 4; ++j) ws[WS_HRES + t * 4 + j] = s.g.x[t * 4 + j];
        }
      }
      tile_fma_store(wq,  s.g.x, col0, row0, ws + WS_QKV,          (float4*)s.g.racc);
      tile_fma_store(wk,  s.g.x, col0, row0, ws + WS_QKV + E_,     (float4*)s.g.racc);
      tile_fma_store(wv4, s.g.x, col0, row0, ws + WS_QKV + 2 * E_, (float4*)s.g.racc);
    }
    gbar(ws, bid);

    // ---- stage attn: one chunk per block; atomics replace the combine stage ----
    attn_stage(p, s, ws, i, bid);
    gbar(ws, bid);

    // ---- stage wo: prefetch Wo tile, THEN merge NACC copies -> x = vals ----
    {
      int col0 = (bid >> 4) * 64, row0 = (bid & 15) * 64;
      float4 wo4[4];
      tile_load(p.Wo + (size_t)i * E_ * E_, col0, row0, wo4);
      int hh = t >> 4;                      // head for elements t*4..t*4+3
      float lsum = 0.f;
#pragma unroll
      for (int c = 0; c < NACC; ++c) lsum += ws[WS_LACC + c * 16 + hh];
      float4 n = make_float4(0,0,0,0);
#pragma unroll
      for (int c = 0; c < NACC; ++c) {
        float4 v = *(const float4*)(ws + WS_NACC + c * E_ + t * 4);
        n.x += v.x; n.y += v.y; n.z += v.z; n.w += v.w;
      }
      s.g.x[t * 4 + 0] = n.x / lsum; s.g.x[t * 4 + 1] = n.y / lsum;
      s.g.x[t * 4 + 2] = n.z / lsum; s.g.x[t * 4 + 3] = n.w / lsum;
      if (bid == 0) {
#pragma unroll
        for (int j = 0; j < 4; ++j) ws[WS_FFT + t * 4 + j] = p.b1[(size_t)i * E_ + t * 4 + j];
      }
      __syncthreads();
      tile_fma_store(wo4, s.g.x, col0, row0, ws + WS_WO, (float4*)s.g.racc);
    }
    gbar(ws, bid);

    // ---- stage w1: prefetch W1 tile, THEN hA = LN1(hres + wo_out) ----
    {
      int col0 = (bid >> 4) * 64, row0 = (bid & 15) * 64;
      float4 w14[4];
      tile_load(p.W1 + (size_t)i * E_ * E_, col0, row0, w14);
      block_ln(ws + WS_HRES, ws + WS_WO, p.ln1s + (size_t)i * E_,
               p.ln1b + (size_t)i * E_, 1e-6f, s.g.x, s.g.red);
      if (bid == 0) {
#pragma unroll
        for (int j = 0; j < 4; ++j) {
          ws[WS_HA + t * 4 + j]  = s.g.x[t * 4 + j];
          ws[WS_FFO + t * 4 + j] = p.b2[(size_t)i * E_ + t * 4 + j];
        }
      }
      tile_fma_store(w14, s.g.x, col0, row0, ws + WS_FFT, (float4*)s.g.racc);
    }
    gbar(ws, bid);

    // ---- stage w2: prefetch W2 tile, THEN x = relu(ff_t); block0 preps next layer ----
    {
      int col0 = (bid >> 4) * 64, row0 = (bid & 15) * 64;
      float4 w24[4];
      tile_load(p.W2 + (size_t)i * E_ * E_, col0, row0, w24);
#pragma unroll
      for (int j = 0; j < 4; ++j) s.g.x[t * 4 + j] = fmaxf(ws[WS_FFT + t * 4 + j], 0.f);
      if (bid == 0 && i != L_ - 1) {
        int nl = i + 1;
#pragma unroll
        for (int j = 0; j < 4; ++j) {
          ws[WS_QKV + t * 4 + j]          = p.bq[(size_t)nl * E_ + t * 4 + j];
          ws[WS_QKV + E_ + t * 4 + j]     = p.bk[(size_t)nl * E_ + t * 4 + j];
          ws[WS_QKV + 2 * E_ + t * 4 + j] = p.bv[(size_t)nl * E_ + t * 4 + j];
          ws[WS_WO + t * 4 + j]           = p.bo[(size_t)nl * E_ + t * 4 + j];
        }
        for (int k = t; k < ACC_FLOATS; k += 256) ws[WS_LACC + k] = 0.f;
      }
      __syncthreads();
      tile_fma_store(w24, s.g.x, col0, row0, ws + WS_FFO, (float4*)s.g.racc);
    }
    gbar(ws, bid);
  }

  if (bid == 0) final_stage(p, s, ws);
}

extern "C" void kernel_launch(void* const* d_in, const int* in_sizes, int n_in,
                              void* d_out, int out_size, void* d_ws, size_t ws_size,
                              hipStream_t stream) {
  (void)in_sizes; (void)n_in; (void)out_size; (void)ws_size;
  Params p;
  p.xi     = (const int*)d_in[0];
  p.cache1 = (const float*)d_in[1];
  p.cache2 = (const float*)d_in[2];
  p.et   = (const float*)d_in[3];
  p.eid  = (const float*)d_in[4];
  p.ex   = (const float*)d_in[5];
  p.ey   = (const float*)d_in[6];
  p.etm  = (const float*)d_in[7];
  p.lnes = (const float*)d_in[8];
  p.lneb = (const float*)d_in[9];
  p.Wv = (const float*)d_in[10];
  p.Wq = (const float*)d_in[11];
  p.Wk = (const float*)d_in[12];
  p.Wo = (const float*)d_in[13];
  p.W1 = (const float*)d_in[14];
  p.W2 = (const float*)d_in[15];
  p.bv = (const float*)d_in[16];
  p.bq = (const float*)d_in[17];
  p.bk = (const float*)d_in[18];
  p.bo = (const float*)d_in[19];
  p.b1 = (const float*)d_in[20];
  p.b2 = (const float*)d_in[21];
  p.ln1s = (const float*)d_in[22];
  p.ln1b = (const float*)d_in[23];
  p.ln2s = (const float*)d_in[24];
  p.ln2b = (const float*)d_in[25];
  p.Wpi = (const float*)d_in[26];
  p.bpi = (const float*)d_in[27];
  p.Wvh = (const float*)d_in[28];
  p.bvh = (const float*)d_in[29];
  p.Wc  = (const float*)d_in[30];
  p.bc  = (const float*)d_in[31];
  p.ws  = (float*)d_ws;
  p.out = (float*)d_out;
  p.oc1 = p.out + 47;
  p.oc2 = p.out + 47 + (size_t)L_ * S_ * E_;

  void* args[] = { &p };
  hipLaunchCooperativeKernel(reinterpret_cast<const void*>(&k_net),
                             dim3(GRID), dim3(256), args, 0, stream);
}